// Round 5
// baseline (520.148 us; speedup 1.0000x reference)
//
#include <hip/hip_runtime.h>
#include <hip/hip_bf16.h>
#include <stdint.h>

#define B_  2
#define T_  2048
#define C_  1024
#define H_  16
#define HD_ 64
#define M_  4096   // B*T
#define FF_ 4096
#define KV_ 128

typedef unsigned short ushort_t;
typedef __bf16 bf16x8 __attribute__((ext_vector_type(8)));
typedef float  f32x4  __attribute__((ext_vector_type(4)));

#define C2_ 0.1803368801111204f   // (1/sqrt(64)) * log2(e)

__device__ inline ushort_t f2bf(float f) {
  uint32_t u = __builtin_bit_cast(uint32_t, f);
  u += 0x7fffu + ((u >> 16) & 1u);
  return (ushort_t)(u >> 16);
}

// async global->LDS, 16B per lane (dwordx4 variant)
__device__ inline void gload_lds16(const void* g, void* l) {
  __builtin_amdgcn_global_load_lds(
      (const __attribute__((address_space(1))) uint32_t*)g,
      (__attribute__((address_space(3))) uint32_t*)l, 16, 0, 0);
}

// 128B-row tiles (64 bf16 cols): slot ^= row&7  -> conflict-free b128 reads
__device__ inline int qswz(int row, int byte_in_row) {
  return row * 128 + (byte_in_row ^ ((row & 7) << 4));
}
// 256B-row tiles (128 bf16 cols): slot ^= ((row&3)<<2) ^ ((row>>2)&3)
// -> minimal bank load for both uint4 writes and b128 fragment reads
__device__ inline int swz256(int row, int byte_in_row) {
  int slot = byte_in_row >> 4;
  int sl = slot ^ ((row & 3) << 2) ^ ((row >> 2) & 3);
  return row * 256 + sl * 16 + (byte_in_row & 15);
}

// ---------------------------------------------------------------- LayerNorm
__global__ __launch_bounds__(256) void lnorm_kernel(
    const float* __restrict__ x, const float* __restrict__ g,
    const float* __restrict__ b, ushort_t* __restrict__ o) {
  int row = blockIdx.x;
  int tid = threadIdx.x;
  const float4* xr = (const float4*)(x + (size_t)row * C_);
  float4 xv = xr[tid];
  float s  = xv.x + xv.y + xv.z + xv.w;
  float s2 = xv.x*xv.x + xv.y*xv.y + xv.z*xv.z + xv.w*xv.w;
#pragma unroll
  for (int off = 32; off; off >>= 1) {
    s  += __shfl_down(s,  off);
    s2 += __shfl_down(s2, off);
  }
  __shared__ float rs[4], rq[4];
  int wid = tid >> 6;
  if ((tid & 63) == 0) { rs[wid] = s; rq[wid] = s2; }
  __syncthreads();
  float tot  = rs[0] + rs[1] + rs[2] + rs[3];
  float tot2 = rq[0] + rq[1] + rq[2] + rq[3];
  float mu   = tot * (1.0f / C_);
  float var  = tot2 * (1.0f / C_) - mu * mu;
  float rstd = rsqrtf(var + 1e-5f);
  float4 gv = ((const float4*)g)[tid];
  float4 bv = ((const float4*)b)[tid];
  float y0 = (xv.x - mu) * rstd * gv.x + bv.x;
  float y1 = (xv.y - mu) * rstd * gv.y + bv.y;
  float y2 = (xv.z - mu) * rstd * gv.z + bv.z;
  float y3 = (xv.w - mu) * rstd * gv.w + bv.w;
  uint2 pk;
  pk.x = (uint32_t)f2bf(y0) | ((uint32_t)f2bf(y1) << 16);
  pk.y = (uint32_t)f2bf(y2) | ((uint32_t)f2bf(y3) << 16);
  *(uint2*)(o + (size_t)row * C_ + tid * 4) = pk;
}

// ------------------------------------------- transpose + f32->bf16 cast of W
__global__ __launch_bounds__(256) void tcast_kernel(
    const float* __restrict__ W, ushort_t* __restrict__ Wt, int K, int N) {
  __shared__ float t[32][33];
  int bn = blockIdx.x, bk = blockIdx.y;
  int tx = threadIdx.x & 31, ty = threadIdx.x >> 5;
#pragma unroll
  for (int i = 0; i < 4; ++i)
    t[ty + i*8][tx] = W[(size_t)(bk*32 + ty + i*8) * N + bn*32 + tx];
  __syncthreads();
#pragma unroll
  for (int i = 0; i < 4; ++i)
    Wt[(size_t)(bn*32 + ty + i*8) * K + bk*32 + tx] = f2bf(t[tx][ty + i*8]);
}

// -------------------------------------- V transpose: qkv V-part -> vt[c][tok]
// vt[(b*16 + h)*64 + d][tok] = qkv[b*T + tok][2048 + h*64 + d]
__global__ __launch_bounds__(256) void vtrans_kernel(
    const ushort_t* __restrict__ qkv, ushort_t* __restrict__ vt) {
  __shared__ ushort_t t[32][33];
  int tt = blockIdx.x;   // tok tile (64)
  int cc = blockIdx.y;   // c tile (32)
  int bb = blockIdx.z;
  int tx = threadIdx.x & 31, ty = threadIdx.x >> 5;
#pragma unroll
  for (int i = 0; i < 4; ++i)
    t[ty + i*8][tx] = qkv[(size_t)(bb*T_ + tt*32 + ty + i*8)*3072 + 2048 + cc*32 + tx];
  __syncthreads();
  int crow = threadIdx.x >> 4;   // 0..15
  int ucol = threadIdx.x & 15;   // uint col (2 toks)
#pragma unroll
  for (int i = 0; i < 2; ++i) {
    int c = crow + i*16;
    uint32_t vlo = t[ucol*2][c], vhi = t[ucol*2 + 1][c];
    *(uint32_t*)&vt[(size_t)(bb*1024 + cc*32 + c)*T_ + tt*32 + ucol*2] =
        vlo | (vhi << 16);
  }
}

// ------------------------------------------------------------------- GEMM
// (unchanged from R4 — verified passing)
template<int BIAS, int RELU, int RESID, int OUTBF16>
__global__ __launch_bounds__(256) void gemm_kernel(
    const ushort_t* __restrict__ A, const ushort_t* __restrict__ Bt,
    const float* __restrict__ bias, const float* __restrict__ resid,
    void* __restrict__ outp, int M, int N, int K) {
  __shared__ __align__(16) ushort_t As[128*32];
  __shared__ __align__(16) ushort_t Bs[128*32];
  int bn = blockIdx.x, bm = blockIdx.y;
  int tid = threadIdx.x;
  int lane = tid & 63, wid = tid >> 6;
  int wr = (wid >> 1) * 64, wc = (wid & 1) * 64;
  int r = lane & 15, g = lane >> 4;
  int srow = tid >> 2, scc = (tid & 3) * 8;
  int srow2 = srow + 64;
  f32x4 acc[4][4] = {};
  int nk = K >> 5;
  for (int kt = 0; kt < nk; ++kt) {
    gload_lds16(&A[(size_t)(bm*128 + srow)  * K + kt*32 + scc], &As[tid*8]);
    gload_lds16(&A[(size_t)(bm*128 + srow2) * K + kt*32 + scc], &As[(tid+256)*8]);
    gload_lds16(&Bt[(size_t)(bn*128 + srow)  * K + kt*32 + scc], &Bs[tid*8]);
    gload_lds16(&Bt[(size_t)(bn*128 + srow2) * K + kt*32 + scc], &Bs[(tid+256)*8]);
    __syncthreads();
    bf16x8 af[4], bfv[4];
#pragma unroll
    for (int m = 0; m < 4; ++m)
      af[m] = *(const bf16x8*)&As[(wr + m*16 + r)*32 + g*8];
#pragma unroll
    for (int n = 0; n < 4; ++n)
      bfv[n] = *(const bf16x8*)&Bs[(wc + n*16 + r)*32 + g*8];
#pragma unroll
    for (int m = 0; m < 4; ++m)
#pragma unroll
      for (int n = 0; n < 4; ++n)
        acc[m][n] = __builtin_amdgcn_mfma_f32_16x16x32_bf16(
            af[m], bfv[n], acc[m][n], 0, 0, 0);
    __syncthreads();
  }
#pragma unroll
  for (int m = 0; m < 4; ++m)
#pragma unroll
    for (int n = 0; n < 4; ++n)
#pragma unroll
      for (int e = 0; e < 4; ++e) {
        int row = bm*128 + wr + m*16 + g*4 + e;
        int col = bn*128 + wc + n*16 + r;
        float v = acc[m][n][e];
        if (BIAS)  v += bias[col];
        if (RESID) v += resid[(size_t)row * N + col];
        if (RELU)  v = fmaxf(v, 0.0f);
        if (OUTBF16) ((ushort_t*)outp)[(size_t)row * N + col] = f2bf(v);
        else         ((float*)outp)[(size_t)row * N + col]    = v;
      }
}

// -------------------------------------------------------- flash attention v2
// KVBLK=128, V^T precomputed globally, reg-prefetch, MFMA row-sums,
// diagonal-only masking, 2 barriers/tile.
__global__ __launch_bounds__(256) void attn_kernel(
    const ushort_t* __restrict__ q, const ushort_t* __restrict__ k,
    const ushort_t* __restrict__ vt, ushort_t* __restrict__ o, int ldq) {
  int bid = blockIdx.x;
  int qb = 31 - (bid & 31);   // LPT: heavy tiles first
  int hh = (bid >> 5) & 15;
  int bb = bid >> 9;
  __shared__ __align__(16) ushort_t Qs[64*64];     // 8 KB, qswz
  __shared__ __align__(16) ushort_t Ks[128*64];    // 16 KB, qswz
  __shared__ __align__(16) ushort_t Vts[64*128];   // 16 KB, swz256 (rows=d)
  __shared__ __align__(16) ushort_t Ps[4][16*128]; // 16 KB, swz256 (per wave)
  int tid = threadIdx.x, lane = tid & 63, w = tid >> 6;
  int r = lane & 15, g = lane >> 4;

  // ---- stage Q (swizzled), then hoist the wave's Q fragments to regs
#pragma unroll
  for (int p = 0; p < 2; ++p) {
    int ci = p*256 + tid;
    int row = ci >> 3, c8 = (ci & 7) * 8;
    *(uint4*)((char*)Qs + qswz(row, c8*2)) =
        *(const uint4*)&q[((size_t)(bb*T_ + qb*64 + row))*ldq + hh*64 + c8];
  }
  __syncthreads();
  bf16x8 aq[2];
#pragma unroll
  for (int ks = 0; ks < 2; ++ks)
    aq[ks] = *(const bf16x8*)((char*)Qs + qswz(w*16 + r, (ks*32 + g*8)*2));

  bf16x8 onesv;
#pragma unroll
  for (int j = 0; j < 8; ++j) onesv[j] = (__bf16)1.0f;

  f32x4 O[4] = {};
  float mrow[4], lrow[4];
#pragma unroll
  for (int e = 0; e < 4; ++e) { mrow[e] = -1e30f; lrow[e] = 0.f; }

  int nkv = (qb*64 + 64 + KV_ - 1) / KV_;

  const ushort_t* kbase = k  + (size_t)bb*T_*ldq + hh*64;
  const ushort_t* vbase = vt + (size_t)((bb*H_ + hh)*HD_) * T_;
  uint4 kreg[4], vreg[4];
  int krow0 = tid >> 3, kslot = tid & 7;    // K: 128 rows x 8 slots
  int vrow0 = tid >> 4, vslot = tid & 15;   // V^T: 64 rows x 16 slots

  // prefetch tile 0
#pragma unroll
  for (int i = 0; i < 4; ++i)
    kreg[i] = *(const uint4*)(kbase + (size_t)(krow0 + i*32)*ldq + kslot*8);
#pragma unroll
  for (int i = 0; i < 4; ++i)
    vreg[i] = *(const uint4*)(vbase + (size_t)(vrow0 + i*16)*T_ + vslot*8);

  for (int kt = 0; kt < nkv; ++kt) {
    __syncthreads();   // prev tile's LDS reads done
    // write prefetched regs -> LDS (swizzled)
#pragma unroll
    for (int i = 0; i < 4; ++i) {
      int row = krow0 + i*32;
      *(uint4*)((char*)Ks + row*128 + ((kslot*16) ^ ((row & 7) << 4))) = kreg[i];
    }
#pragma unroll
    for (int i = 0; i < 4; ++i) {
      int d = vrow0 + i*16;
      int sl = vslot ^ ((d & 3) << 2) ^ ((d >> 2) & 3);
      *(uint4*)((char*)Vts + d*256 + sl*16) = vreg[i];
    }
    __syncthreads();   // LDS ready
    if (kt + 1 < nkv) {   // issue next tile's loads; consumed next iter
#pragma unroll
      for (int i = 0; i < 4; ++i)
        kreg[i] = *(const uint4*)(kbase + (size_t)((kt+1)*KV_ + krow0 + i*32)*ldq + kslot*8);
#pragma unroll
      for (int i = 0; i < 4; ++i)
        vreg[i] = *(const uint4*)(vbase + (size_t)(vrow0 + i*16)*T_ + (kt+1)*KV_ + vslot*8);
    }

    // ---- QK^T: 16 queries x 128 keys
    f32x4 s[8];
#pragma unroll
    for (int n = 0; n < 8; ++n) s[n] = (f32x4){0.f, 0.f, 0.f, 0.f};
#pragma unroll
    for (int ks = 0; ks < 2; ++ks)
#pragma unroll
      for (int n = 0; n < 8; ++n) {
        bf16x8 bk = *(const bf16x8*)((char*)Ks + qswz(n*16 + r, (ks*32 + g*8)*2));
        s[n] = __builtin_amdgcn_mfma_f32_16x16x32_bf16(aq[ks], bk, s[n], 0, 0, 0);
      }

    // ---- online softmax (raw-score max domain, scale folded into exp2)
    bool lastt = (kt == nkv - 1);
#pragma unroll
    for (int e = 0; e < 4; ++e) {
      float mx = -1e30f;
      if (lastt) {
        int qrow = qb*64 + w*16 + g*4 + e;
#pragma unroll
        for (int n = 0; n < 8; ++n) {
          float sv = s[n][e];
          if (kt*KV_ + n*16 + r > qrow) sv = -1e30f;
          s[n][e] = sv;
          mx = fmaxf(mx, sv);
        }
      } else {
#pragma unroll
        for (int n = 0; n < 8; ++n) mx = fmaxf(mx, s[n][e]);
      }
#pragma unroll
      for (int off = 1; off < 16; off <<= 1)
        mx = fmaxf(mx, __shfl_xor(mx, off, 16));
      float mnew = fmaxf(mrow[e], mx);
      float sfe = exp2f((mrow[e] - mnew) * C2_);
      mrow[e] = mnew;
      float mc = mnew * C2_;
#pragma unroll
      for (int n = 0; n < 8; ++n) {
        float p = exp2f(s[n][e] * C2_ - mc);
        *(ushort_t*)((char*)&Ps[w][0] + swz256(g*4 + e, (n*16 + r)*2)) = f2bf(p);
      }
      lrow[e] *= sfe;
#pragma unroll
      for (int dn = 0; dn < 4; ++dn) O[dn][e] *= sfe;
    }

    // ---- PV + row-sums via ones-MFMA (Ps is per-wave: lgkmcnt orders it)
    f32x4 sums = (f32x4){0.f, 0.f, 0.f, 0.f};
#pragma unroll
    for (int ks2 = 0; ks2 < 4; ++ks2) {
      bf16x8 ap = *(const bf16x8*)((char*)&Ps[w][0] + swz256(r, ks2*64 + g*16));
      sums = __builtin_amdgcn_mfma_f32_16x16x32_bf16(ap, onesv, sums, 0, 0, 0);
#pragma unroll
      for (int dn = 0; dn < 4; ++dn) {
        bf16x8 bv = *(const bf16x8*)((char*)Vts + swz256(dn*16 + r, ks2*64 + g*16));
        O[dn] = __builtin_amdgcn_mfma_f32_16x16x32_bf16(ap, bv, O[dn], 0, 0, 0);
      }
    }
#pragma unroll
    for (int e = 0; e < 4; ++e) lrow[e] += sums[e];
  }

#pragma unroll
  for (int dn = 0; dn < 4; ++dn)
#pragma unroll
    for (int e = 0; e < 4; ++e) {
      int tok = qb*64 + w*16 + g*4 + e;
      int col = hh*64 + dn*16 + r;
      o[((size_t)(bb*T_ + tok))*C_ + col] = f2bf(O[dn][e] / lrow[e]);
    }
}

// ----------------------------------------------------------------- launch
extern "C" void kernel_launch(void* const* d_in, const int* in_sizes, int n_in,
                              void* d_out, int out_size, void* d_ws, size_t ws_size,
                              hipStream_t stream) {
  const float* x    = (const float*)d_in[0];
  const float* Wq   = (const float*)d_in[1];
  const float* Wk   = (const float*)d_in[2];
  const float* Wv   = (const float*)d_in[3];
  const float* Wo   = (const float*)d_in[4];
  const float* bo   = (const float*)d_in[5];
  const float* ln1g = (const float*)d_in[6];
  const float* ln1b = (const float*)d_in[7];
  const float* ln2g = (const float*)d_in[8];
  const float* ln2b = (const float*)d_in[9];
  const float* W1   = (const float*)d_in[10];
  const float* b1   = (const float*)d_in[11];
  const float* W2   = (const float*)d_in[12];
  const float* b2   = (const float*)d_in[13];

  char* ws = (char*)d_ws;
  // layout (MB): h@0 (8) -> vt@0 after QKV GEMM (h dead; ff@0 written later)
  // qkv@8 (24) | ff@0 aliases (32) | attn@32 (8), x2@40 (f32,16), h2@56 (8),
  // weights@64..88
  ushort_t* h    = (ushort_t*)(ws + ((size_t)0  << 20));
  ushort_t* vt   = (ushort_t*)(ws + ((size_t)0  << 20));  // aliases h (dead)
  ushort_t* qkv  = (ushort_t*)(ws + ((size_t)8  << 20));
  ushort_t* ff   = (ushort_t*)(ws + ((size_t)0  << 20));
  ushort_t* attn = (ushort_t*)(ws + ((size_t)32 << 20));
  float*    x2   = (float*)   (ws + ((size_t)40 << 20));
  ushort_t* h2   = (ushort_t*)(ws + ((size_t)56 << 20));
  ushort_t* wqt  = (ushort_t*)(ws + ((size_t)64 << 20));  // [3072][1024] fused
  ushort_t* wkt  = (ushort_t*)(ws + ((size_t)66 << 20));
  ushort_t* wvt  = (ushort_t*)(ws + ((size_t)68 << 20));
  ushort_t* wot  = (ushort_t*)(ws + ((size_t)70 << 20));
  ushort_t* w1t  = (ushort_t*)(ws + ((size_t)72 << 20));
  ushort_t* w2t  = (ushort_t*)(ws + ((size_t)80 << 20));
  float* out = (float*)d_out;

  tcast_kernel<<<dim3(32, 32),  256, 0, stream>>>(Wq, wqt, 1024, 1024);
  tcast_kernel<<<dim3(32, 32),  256, 0, stream>>>(Wk, wkt, 1024, 1024);
  tcast_kernel<<<dim3(32, 32),  256, 0, stream>>>(Wv, wvt, 1024, 1024);
  tcast_kernel<<<dim3(32, 32),  256, 0, stream>>>(Wo, wot, 1024, 1024);
  tcast_kernel<<<dim3(128, 32), 256, 0, stream>>>(W1, w1t, 1024, 4096);
  tcast_kernel<<<dim3(32, 128), 256, 0, stream>>>(W2, w2t, 4096, 1024);

  lnorm_kernel<<<M_, 256, 0, stream>>>(x, ln1g, ln1b, h);

  // fused QKV: qkv[M][3072] = h @ [Wq|Wk|Wv]
  gemm_kernel<0,0,0,1><<<dim3(24, 32), 256, 0, stream>>>(h, wqt, nullptr, nullptr, qkv, M_, 3*C_, C_);

  // V^T pre-pass (h is dead now; vt aliases it)
  vtrans_kernel<<<dim3(64, 32, 2), 256, 0, stream>>>(qkv, vt);

  attn_kernel<<<B_*H_*(T_/64), 256, 0, stream>>>(qkv, qkv + C_, vt, attn, 3*C_);

  // x2 = x + attn @ Wo + bo   (f32)
  gemm_kernel<1,0,1,0><<<dim3(8, 32), 256, 0, stream>>>(attn, wot, bo, x, x2, M_, C_, C_);

  lnorm_kernel<<<M_, 256, 0, stream>>>(x2, ln2g, ln2b, h2);

  // ff = relu(h2 @ W1 + b1)  (bf16)
  gemm_kernel<1,1,0,1><<<dim3(32, 32), 256, 0, stream>>>(h2, w1t, b1, nullptr, ff, M_, FF_, C_);

  // out = x2 + ff @ W2 + b2  (f32)
  gemm_kernel<1,0,1,0><<<dim3(8, 32), 256, 0, stream>>>(ff, w2t, b2, x2, out, M_, C_, FF_);
}

// Round 7
// 457.027 us; speedup vs baseline: 1.1381x; 1.1381x over previous
//
#include <hip/hip_runtime.h>
#include <hip/hip_bf16.h>
#include <stdint.h>

#define B_  2
#define T_  2048
#define C_  1024
#define H_  16
#define HD_ 64
#define M_  4096   // B*T
#define FF_ 4096

typedef unsigned short ushort_t;
typedef __bf16 bf16x8 __attribute__((ext_vector_type(8)));
typedef float  f32x4  __attribute__((ext_vector_type(4)));
typedef float  f32x16 __attribute__((ext_vector_type(16)));
typedef unsigned int u32x2 __attribute__((ext_vector_type(2)));
typedef unsigned int u32x4 __attribute__((ext_vector_type(4)));

#define C2_ 0.1803368801111204f   // (1/sqrt(64)) * log2(e)

__device__ inline ushort_t f2bf(float f) {
  uint32_t u = __builtin_bit_cast(uint32_t, f);
  u += 0x7fffu + ((u >> 16) & 1u);
  return (ushort_t)(u >> 16);
}
__device__ inline uint32_t pk2(float lo, float hi) {
  return (uint32_t)f2bf(lo) | ((uint32_t)f2bf(hi) << 16);
}

// async global->LDS, 16B per lane (dwordx4 variant)
__device__ inline void gload_lds16(const void* g, void* l) {
  __builtin_amdgcn_global_load_lds(
      (const __attribute__((address_space(1))) uint32_t*)g,
      (__attribute__((address_space(3))) uint32_t*)l, 16, 0, 0);
}

// 128B-row LDS tiles (64 bf16 cols): logical col-slot c lives at phys slot
// c ^ (row&7). Writes are DMA-linear with pre-swizzled SOURCE; reads use this.
__device__ inline int qswz(int row, int byte_in_row) {
  return row * 128 + (byte_in_row ^ ((row & 7) << 4));
}

// ---------------------------------------------------------------- LayerNorm
__global__ __launch_bounds__(256) void lnorm_kernel(
    const float* __restrict__ x, const float* __restrict__ g,
    const float* __restrict__ b, ushort_t* __restrict__ o) {
  int row = blockIdx.x;
  int tid = threadIdx.x;
  const float4* xr = (const float4*)(x + (size_t)row * C_);
  float4 xv = xr[tid];
  float s  = xv.x + xv.y + xv.z + xv.w;
  float s2 = xv.x*xv.x + xv.y*xv.y + xv.z*xv.z + xv.w*xv.w;
#pragma unroll
  for (int off = 32; off; off >>= 1) {
    s  += __shfl_down(s,  off);
    s2 += __shfl_down(s2, off);
  }
  __shared__ float rs[4], rq[4];
  int wid = tid >> 6;
  if ((tid & 63) == 0) { rs[wid] = s; rq[wid] = s2; }
  __syncthreads();
  float tot  = rs[0] + rs[1] + rs[2] + rs[3];
  float tot2 = rq[0] + rq[1] + rq[2] + rq[3];
  float mu   = tot * (1.0f / C_);
  float var  = tot2 * (1.0f / C_) - mu * mu;
  float rstd = rsqrtf(var + 1e-5f);
  float4 gv = ((const float4*)g)[tid];
  float4 bv = ((const float4*)b)[tid];
  float y0 = (xv.x - mu) * rstd * gv.x + bv.x;
  float y1 = (xv.y - mu) * rstd * gv.y + bv.y;
  float y2 = (xv.z - mu) * rstd * gv.z + bv.z;
  float y3 = (xv.w - mu) * rstd * gv.w + bv.w;
  uint2 pk;
  pk.x = (uint32_t)f2bf(y0) | ((uint32_t)f2bf(y1) << 16);
  pk.y = (uint32_t)f2bf(y2) | ((uint32_t)f2bf(y3) << 16);
  *(uint2*)(o + (size_t)row * C_ + tid * 4) = pk;
}

// ------------------------------------------- transpose + f32->bf16 cast of W
__global__ __launch_bounds__(256) void tcast_kernel(
    const float* __restrict__ W, ushort_t* __restrict__ Wt, int K, int N) {
  __shared__ float t[32][33];
  int bn = blockIdx.x, bk = blockIdx.y;
  int tx = threadIdx.x & 31, ty = threadIdx.x >> 5;
#pragma unroll
  for (int i = 0; i < 4; ++i)
    t[ty + i*8][tx] = W[(size_t)(bk*32 + ty + i*8) * N + bn*32 + tx];
  __syncthreads();
#pragma unroll
  for (int i = 0; i < 4; ++i)
    Wt[(size_t)(bn*32 + ty + i*8) * K + bk*32 + tx] = f2bf(t[tx][ty + i*8]);
}

// -------------------------------------- V transpose: qkv V-part -> vt[c][tok]
__global__ __launch_bounds__(256) void vtrans_kernel(
    const ushort_t* __restrict__ qkv, ushort_t* __restrict__ vt) {
  __shared__ ushort_t t[32][33];
  int tt = blockIdx.x;   // tok tile (32)
  int cc = blockIdx.y;   // c tile (32)
  int bb = blockIdx.z;
  int tx = threadIdx.x & 31, ty = threadIdx.x >> 5;
#pragma unroll
  for (int i = 0; i < 4; ++i)
    t[ty + i*8][tx] = qkv[(size_t)(bb*T_ + tt*32 + ty + i*8)*3072 + 2048 + cc*32 + tx];
  __syncthreads();
  int crow = threadIdx.x >> 4;
  int ucol = threadIdx.x & 15;
#pragma unroll
  for (int i = 0; i < 2; ++i) {
    int c = crow + i*16;
    uint32_t vlo = t[ucol*2][c], vhi = t[ucol*2 + 1][c];
    *(uint32_t*)&vt[(size_t)(bb*1024 + cc*32 + c)*T_ + tt*32 + ucol*2] =
        vlo | (vhi << 16);
  }
}

// ------------------------------------------------------------------- GEMM
// (unchanged — verified passing R3/R4)
template<int BIAS, int RELU, int RESID, int OUTBF16>
__global__ __launch_bounds__(256) void gemm_kernel(
    const ushort_t* __restrict__ A, const ushort_t* __restrict__ Bt,
    const float* __restrict__ bias, const float* __restrict__ resid,
    void* __restrict__ outp, int M, int N, int K) {
  __shared__ __align__(16) ushort_t As[128*32];
  __shared__ __align__(16) ushort_t Bs[128*32];
  int bn = blockIdx.x, bm = blockIdx.y;
  int tid = threadIdx.x;
  int lane = tid & 63, wid = tid >> 6;
  int wr = (wid >> 1) * 64, wc = (wid & 1) * 64;
  int r = lane & 15, g = lane >> 4;
  int srow = tid >> 2, scc = (tid & 3) * 8;
  int srow2 = srow + 64;
  f32x4 acc[4][4] = {};
  int nk = K >> 5;
  for (int kt = 0; kt < nk; ++kt) {
    gload_lds16(&A[(size_t)(bm*128 + srow)  * K + kt*32 + scc], &As[tid*8]);
    gload_lds16(&A[(size_t)(bm*128 + srow2) * K + kt*32 + scc], &As[(tid+256)*8]);
    gload_lds16(&Bt[(size_t)(bn*128 + srow)  * K + kt*32 + scc], &Bs[tid*8]);
    gload_lds16(&Bt[(size_t)(bn*128 + srow2) * K + kt*32 + scc], &Bs[(tid+256)*8]);
    __syncthreads();
    bf16x8 af[4], bfv[4];
#pragma unroll
    for (int m = 0; m < 4; ++m)
      af[m] = *(const bf16x8*)&As[(wr + m*16 + r)*32 + g*8];
#pragma unroll
    for (int n = 0; n < 4; ++n)
      bfv[n] = *(const bf16x8*)&Bs[(wc + n*16 + r)*32 + g*8];
#pragma unroll
    for (int m = 0; m < 4; ++m)
#pragma unroll
      for (int n = 0; n < 4; ++n)
        acc[m][n] = __builtin_amdgcn_mfma_f32_16x16x32_bf16(
            af[m], bfv[n], acc[m][n], 0, 0, 0);
    __syncthreads();
  }
#pragma unroll
  for (int m = 0; m < 4; ++m)
#pragma unroll
    for (int n = 0; n < 4; ++n)
#pragma unroll
      for (int e = 0; e < 4; ++e) {
        int row = bm*128 + wr + m*16 + g*4 + e;
        int col = bn*128 + wc + n*16 + r;
        float v = acc[m][n][e];
        if (BIAS)  v += bias[col];
        if (RESID) v += resid[(size_t)row * N + col];
        if (RELU)  v = fmaxf(v, 0.0f);
        if (OUTBF16) ((ushort_t*)outp)[(size_t)row * N + col] = f2bf(v);
        else         ((float*)outp)[(size_t)row * N + col]    = v;
      }
}

// -------------------------------------------------------- flash attention v3
// Swapped QK^T (mfma(K,Q) -> D[key][q]), in-register softmax (q = lane&31),
// partner-lane P repack via shfl_xor(32), PV as O^T = mfma(Vt, P).
// 4 waves x 32 q-rows (QBLK=128), KVBLK=64, LDS = Ks+Vts = 16KB, DMA-staged
// with pre-swizzled source (linear dest) + qswz reads.
__global__ __launch_bounds__(256) void attn_kernel(
    const ushort_t* __restrict__ q, const ushort_t* __restrict__ k,
    const ushort_t* __restrict__ vt, ushort_t* __restrict__ o, int ldq) {
  int bid = blockIdx.x;
  int qbb = 15 - (bid & 15);   // LPT: heavy q-blocks first
  int hh = (bid >> 4) & 15;
  int bb = bid >> 8;
  __shared__ __align__(16) ushort_t Ks[64*64];
  __shared__ __align__(16) ushort_t Vts[64*64];
  int tid = threadIdx.x, lane = tid & 63, w = tid >> 6;
  int qi = lane & 31, hi = lane >> 5;
  int qrow0 = qbb*128 + w*32;
  int qg = qrow0 + qi;                 // this lane's query row (in sequence)
  int lt = 2*qbb + (w >> 1);           // wave's last (diagonal) KV tile
  int nkv = 2*qbb + 2;

  // Q fragments direct to regs: B-frag = Q[qg][c*16 + hi*8 + 0..7]
  const ushort_t* qbase = q + ((size_t)(bb*T_ + qg))*ldq + hh*64;
  bf16x8 qv[4];
#pragma unroll
  for (int c = 0; c < 4; ++c)
    qv[c] = *(const bf16x8*)(qbase + c*16 + hi*8);

  const ushort_t* kbase = k  + ((size_t)bb*T_)*ldq + hh*64;
  const ushort_t* vbase = vt + ((size_t)(bb*1024 + hh*64))*T_;

  int r0s = tid >> 3;                       // staging row 0..31
  int s0  = ((tid & 7) ^ (r0s & 7)) * 8;    // pre-swizzled source col (elems)

  f32x16 O0 = {}, O1 = {};
  float mrun = -1e30f, lrun = 0.f;

  for (int kt = 0; kt < nkv; ++kt) {
    // stage K,V tiles: DMA linear dest, swizzled global source
    gload_lds16(kbase + ((size_t)(kt*64 + r0s))*ldq + s0,      &Ks[tid*8]);
    gload_lds16(kbase + ((size_t)(kt*64 + r0s + 32))*ldq + s0, &Ks[(tid+256)*8]);
    gload_lds16(vbase + (size_t)r0s*T_ + kt*64 + s0,           &Vts[tid*8]);
    gload_lds16(vbase + (size_t)(r0s+32)*T_ + kt*64 + s0,      &Vts[(tid+256)*8]);
    __syncthreads();
    if (kt <= lt) {   // wave-uniform
      // ---- QK^T swapped: a0 = keys 0..31, a1 = keys 32..63 (rows), q = col
      f32x16 a0 = {}, a1 = {};
#pragma unroll
      for (int c = 0; c < 4; ++c) {
        bf16x8 k0 = *(const bf16x8*)((char*)Ks + qswz(qi,      c*32 + hi*16));
        bf16x8 k1 = *(const bf16x8*)((char*)Ks + qswz(32 + qi, c*32 + hi*16));
        a0 = __builtin_amdgcn_mfma_f32_32x32x16_bf16(k0, qv[c], a0, 0, 0, 0);
        a1 = __builtin_amdgcn_mfma_f32_32x32x16_bf16(k1, qv[c], a1, 0, 0, 0);
      }
      // ---- causal mask (diagonal tile only); key = kof + (rg&3)+8*(rg>>2)
      if (kt == lt) {
        int kof = kt*64 + 4*hi;
#pragma unroll
        for (int rg = 0; rg < 16; ++rg) {
          int kp = kof + (rg & 3) + 8*(rg >> 2);
          if (kp > qg)      a0[rg] = -1e30f;
          if (kp + 32 > qg) a1[rg] = -1e30f;
        }
      }
      // ---- in-register online softmax (row = this lane's query)
      float tm = -1e30f;
#pragma unroll
      for (int rg = 0; rg < 16; ++rg) tm = fmaxf(tm, fmaxf(a0[rg], a1[rg]));
      tm = fmaxf(tm, __shfl_xor(tm, 32));
      float mnew = fmaxf(mrun, tm);
      float sf = exp2f((mrun - mnew) * C2_);
      mrun = mnew;
      float mc = mnew * C2_;
#pragma unroll
      for (int rg = 0; rg < 16; ++rg) {
        a0[rg] = exp2f(a0[rg]*C2_ - mc);
        a1[rg] = exp2f(a1[rg]*C2_ - mc);
      }
      float rs = 0.f;
#pragma unroll
      for (int rg = 0; rg < 16; ++rg) rs += a0[rg] + a1[rg];
      rs += __shfl_xor(rs, 32);
      lrun = lrun*sf + rs;
#pragma unroll
      for (int rg = 0; rg < 16; ++rg) { O0[rg] *= sf; O1[rg] *= sf; }
      // ---- repack P to B-frags via partner exchange (lane <-> lane^32)
      bf16x8 pf[4];
#pragma unroll
      for (int kb = 0; kb < 2; ++kb)
#pragma unroll
        for (int jj = 0; jj < 2; ++jj) {
          int rb = jj*8;
          float v0 = kb ? a1[rb+0] : a0[rb+0], v1 = kb ? a1[rb+1] : a0[rb+1];
          float v2 = kb ? a1[rb+2] : a0[rb+2], v3 = kb ? a1[rb+3] : a0[rb+3];
          float v4 = kb ? a1[rb+4] : a0[rb+4], v5 = kb ? a1[rb+5] : a0[rb+5];
          float v6 = kb ? a1[rb+6] : a0[rb+6], v7 = kb ? a1[rb+7] : a0[rb+7];
          uint32_t d0 = pk2(v0, v1), d1 = pk2(v2, v3);
          uint32_t e0 = pk2(v4, v5), e1 = pk2(v6, v7);
          uint32_t pd0 = __shfl_xor(d0, 32), pd1 = __shfl_xor(d1, 32);
          uint32_t pe0 = __shfl_xor(e0, 32), pe1 = __shfl_xor(e1, 32);
          u32x4 fw;
          fw[0] = hi ? pe0 : d0;
          fw[1] = hi ? pe1 : d1;
          fw[2] = hi ? e0  : pd0;
          fw[3] = hi ? e1  : pd1;
          pf[kb*2 + jj] = __builtin_bit_cast(bf16x8, fw);
        }
      // ---- PV: O^T[d][q] += Vt-frag x P-frag  (q stays lane-local)
#pragma unroll
      for (int kk = 0; kk < 4; ++kk) {
        bf16x8 vv0 = *(const bf16x8*)((char*)Vts + qswz(qi,      kk*32 + hi*16));
        bf16x8 vv1 = *(const bf16x8*)((char*)Vts + qswz(32 + qi, kk*32 + hi*16));
        O0 = __builtin_amdgcn_mfma_f32_32x32x16_bf16(vv0, pf[kk], O0, 0, 0, 0);
        O1 = __builtin_amdgcn_mfma_f32_32x32x16_bf16(vv1, pf[kk], O1, 0, 0, 0);
      }
    }
    __syncthreads();
  }
  // ---- epilogue: O[d][q]/l -> o[tok][col], d = (rg&3)+8*(rg>>2)+4hi (+32 O1)
  float inv = 1.0f / lrun;
  ushort_t* ob = o + ((size_t)(bb*T_ + qg))*C_ + hh*64;
#pragma unroll
  for (int tq = 0; tq < 4; ++tq) {
    u32x2 st0, st1;
    st0[0] = pk2(O0[4*tq+0]*inv, O0[4*tq+1]*inv);
    st0[1] = pk2(O0[4*tq+2]*inv, O0[4*tq+3]*inv);
    st1[0] = pk2(O1[4*tq+0]*inv, O1[4*tq+1]*inv);
    st1[1] = pk2(O1[4*tq+2]*inv, O1[4*tq+3]*inv);
    *(u32x2*)(ob + 8*tq + 4*hi)      = st0;
    *(u32x2*)(ob + 32 + 8*tq + 4*hi) = st1;
  }
}

// ----------------------------------------------------------------- launch
extern "C" void kernel_launch(void* const* d_in, const int* in_sizes, int n_in,
                              void* d_out, int out_size, void* d_ws, size_t ws_size,
                              hipStream_t stream) {
  const float* x    = (const float*)d_in[0];
  const float* Wq   = (const float*)d_in[1];
  const float* Wk   = (const float*)d_in[2];
  const float* Wv   = (const float*)d_in[3];
  const float* Wo   = (const float*)d_in[4];
  const float* bo   = (const float*)d_in[5];
  const float* ln1g = (const float*)d_in[6];
  const float* ln1b = (const float*)d_in[7];
  const float* ln2g = (const float*)d_in[8];
  const float* ln2b = (const float*)d_in[9];
  const float* W1   = (const float*)d_in[10];
  const float* b1   = (const float*)d_in[11];
  const float* W2   = (const float*)d_in[12];
  const float* b2   = (const float*)d_in[13];

  char* ws = (char*)d_ws;
  ushort_t* h    = (ushort_t*)(ws + ((size_t)0  << 20));
  ushort_t* vt   = (ushort_t*)(ws + ((size_t)0  << 20));  // aliases h (dead)
  ushort_t* qkv  = (ushort_t*)(ws + ((size_t)8  << 20));
  ushort_t* ff   = (ushort_t*)(ws + ((size_t)0  << 20));
  ushort_t* attn = (ushort_t*)(ws + ((size_t)32 << 20));
  float*    x2   = (float*)   (ws + ((size_t)40 << 20));
  ushort_t* h2   = (ushort_t*)(ws + ((size_t)56 << 20));
  ushort_t* wqt  = (ushort_t*)(ws + ((size_t)64 << 20));  // [3072][1024] fused
  ushort_t* wkt  = (ushort_t*)(ws + ((size_t)66 << 20));
  ushort_t* wvt  = (ushort_t*)(ws + ((size_t)68 << 20));
  ushort_t* wot  = (ushort_t*)(ws + ((size_t)70 << 20));
  ushort_t* w1t  = (ushort_t*)(ws + ((size_t)72 << 20));
  ushort_t* w2t  = (ushort_t*)(ws + ((size_t)80 << 20));
  float* out = (float*)d_out;

  tcast_kernel<<<dim3(32, 32),  256, 0, stream>>>(Wq, wqt, 1024, 1024);
  tcast_kernel<<<dim3(32, 32),  256, 0, stream>>>(Wk, wkt, 1024, 1024);
  tcast_kernel<<<dim3(32, 32),  256, 0, stream>>>(Wv, wvt, 1024, 1024);
  tcast_kernel<<<dim3(32, 32),  256, 0, stream>>>(Wo, wot, 1024, 1024);
  tcast_kernel<<<dim3(128, 32), 256, 0, stream>>>(W1, w1t, 1024, 4096);
  tcast_kernel<<<dim3(32, 128), 256, 0, stream>>>(W2, w2t, 4096, 1024);

  lnorm_kernel<<<M_, 256, 0, stream>>>(x, ln1g, ln1b, h);

  // fused QKV: qkv[M][3072] = h @ [Wq|Wk|Wv]
  gemm_kernel<0,0,0,1><<<dim3(24, 32), 256, 0, stream>>>(h, wqt, nullptr, nullptr, qkv, M_, 3*C_, C_);

  // V^T pre-pass (h dead; vt aliases it)
  vtrans_kernel<<<dim3(64, 32, 2), 256, 0, stream>>>(qkv, vt);

  attn_kernel<<<512, 256, 0, stream>>>(qkv, qkv + C_, vt, attn, 3*C_);

  // x2 = x + attn @ Wo + bo   (f32)
  gemm_kernel<1,0,1,0><<<dim3(8, 32), 256, 0, stream>>>(attn, wot, bo, x, x2, M_, C_, C_);

  lnorm_kernel<<<M_, 256, 0, stream>>>(x2, ln2g, ln2b, h2);

  // ff = relu(h2 @ W1 + b1)  (bf16)
  gemm_kernel<1,1,0,1><<<dim3(32, 32), 256, 0, stream>>>(h2, w1t, b1, nullptr, ff, M_, FF_, C_);

  // out = x2 + ff @ W2 + b2  (f32)
  gemm_kernel<1,0,1,0><<<dim3(8, 32), 256, 0, stream>>>(ff, w2t, b2, x2, out, M_, C_, FF_);
}

// Round 9
// 421.806 us; speedup vs baseline: 1.2331x; 1.0835x over previous
//
#include <hip/hip_runtime.h>
#include <hip/hip_bf16.h>
#include <stdint.h>

#define B_  2
#define T_  2048
#define C_  1024
#define H_  16
#define HD_ 64
#define M_  4096   // B*T
#define FF_ 4096

typedef unsigned short ushort_t;
typedef __bf16 bf16x8 __attribute__((ext_vector_type(8)));
typedef float  f32x4  __attribute__((ext_vector_type(4)));
typedef float  f32x16 __attribute__((ext_vector_type(16)));
typedef unsigned int u32x2 __attribute__((ext_vector_type(2)));
typedef unsigned int u32x4 __attribute__((ext_vector_type(4)));

#define C2_ 0.1803368801111204f   // (1/sqrt(64)) * log2(e)

__device__ inline ushort_t f2bf(float f) {
  uint32_t u = __builtin_bit_cast(uint32_t, f);
  u += 0x7fffu + ((u >> 16) & 1u);
  return (ushort_t)(u >> 16);
}
__device__ inline uint32_t pk2(float lo, float hi) {
  return (uint32_t)f2bf(lo) | ((uint32_t)f2bf(hi) << 16);
}

// async global->LDS, 16B per lane (dwordx4 variant)
__device__ inline void gload_lds16(const void* g, void* l) {
  __builtin_amdgcn_global_load_lds(
      (const __attribute__((address_space(1))) uint32_t*)g,
      (__attribute__((address_space(3))) uint32_t*)l, 16, 0, 0);
}

// 128B-row LDS tiles (64 bf16 cols): logical col-slot c lives at phys slot
// c ^ (row&7). Writes are DMA-linear with pre-swizzled SOURCE; reads use this.
__device__ inline int qswz(int row, int byte_in_row) {
  return row * 128 + (byte_in_row ^ ((row & 7) << 4));
}

// ---------------------------------------------------------------- LayerNorm
__global__ __launch_bounds__(256) void lnorm_kernel(
    const float* __restrict__ x, const float* __restrict__ g,
    const float* __restrict__ b, ushort_t* __restrict__ o) {
  int row = blockIdx.x;
  int tid = threadIdx.x;
  const float4* xr = (const float4*)(x + (size_t)row * C_);
  float4 xv = xr[tid];
  float s  = xv.x + xv.y + xv.z + xv.w;
  float s2 = xv.x*xv.x + xv.y*xv.y + xv.z*xv.z + xv.w*xv.w;
#pragma unroll
  for (int off = 32; off; off >>= 1) {
    s  += __shfl_down(s,  off);
    s2 += __shfl_down(s2, off);
  }
  __shared__ float rs[4], rq[4];
  int wid = tid >> 6;
  if ((tid & 63) == 0) { rs[wid] = s; rq[wid] = s2; }
  __syncthreads();
  float tot  = rs[0] + rs[1] + rs[2] + rs[3];
  float tot2 = rq[0] + rq[1] + rq[2] + rq[3];
  float mu   = tot * (1.0f / C_);
  float var  = tot2 * (1.0f / C_) - mu * mu;
  float rstd = rsqrtf(var + 1e-5f);
  float4 gv = ((const float4*)g)[tid];
  float4 bv = ((const float4*)b)[tid];
  float y0 = (xv.x - mu) * rstd * gv.x + bv.x;
  float y1 = (xv.y - mu) * rstd * gv.y + bv.y;
  float y2 = (xv.z - mu) * rstd * gv.z + bv.z;
  float y3 = (xv.w - mu) * rstd * gv.w + bv.w;
  uint2 pk;
  pk.x = (uint32_t)f2bf(y0) | ((uint32_t)f2bf(y1) << 16);
  pk.y = (uint32_t)f2bf(y2) | ((uint32_t)f2bf(y3) << 16);
  *(uint2*)(o + (size_t)row * C_ + tid * 4) = pk;
}

// ------------------------------------------- transpose + f32->bf16 cast of W
__global__ __launch_bounds__(256) void tcast_kernel(
    const float* __restrict__ W, ushort_t* __restrict__ Wt, int K, int N) {
  __shared__ float t[32][33];
  int bn = blockIdx.x, bk = blockIdx.y;
  int tx = threadIdx.x & 31, ty = threadIdx.x >> 5;
#pragma unroll
  for (int i = 0; i < 4; ++i)
    t[ty + i*8][tx] = W[(size_t)(bk*32 + ty + i*8) * N + bn*32 + tx];
  __syncthreads();
#pragma unroll
  for (int i = 0; i < 4; ++i)
    Wt[(size_t)(bn*32 + ty + i*8) * K + bk*32 + tx] = f2bf(t[tx][ty + i*8]);
}

// -------------------------------------- V transpose: qkv V-part -> vt[c][tok]
__global__ __launch_bounds__(256) void vtrans_kernel(
    const ushort_t* __restrict__ qkv, ushort_t* __restrict__ vt) {
  __shared__ ushort_t t[32][33];
  int tt = blockIdx.x;   // tok tile (32)
  int cc = blockIdx.y;   // c tile (32)
  int bb = blockIdx.z;
  int tx = threadIdx.x & 31, ty = threadIdx.x >> 5;
#pragma unroll
  for (int i = 0; i < 4; ++i)
    t[ty + i*8][tx] = qkv[(size_t)(bb*T_ + tt*32 + ty + i*8)*3072 + 2048 + cc*32 + tx];
  __syncthreads();
  int crow = threadIdx.x >> 4;
  int ucol = threadIdx.x & 15;
#pragma unroll
  for (int i = 0; i < 2; ++i) {
    int c = crow + i*16;
    uint32_t vlo = t[ucol*2][c], vhi = t[ucol*2 + 1][c];
    *(uint32_t*)&vt[(size_t)(bb*1024 + cc*32 + c)*T_ + tt*32 + ucol*2] =
        vlo | (vhi << 16);
  }
}

// ------------------------------------------------------------------- GEMM
// C[M][N] = A[M][K](bf16) @ Bt[N][K](bf16)^T  (+bias)(+resid f32)(relu)
// BMx(BN) block tile (BM=128, BN=128|64), BK=32, 4 waves, 16x16x32 MFMA.
// 2-phase double-buffered staging via global_load_lds: STAGE(t+1) issued
// before compute(t); ONE barrier per K-iter (drains vmcnt+lgkm).
template<int BN, int BIAS, int RELU, int RESID, int OUTBF16>
__global__ __launch_bounds__(256) void gemm_kernel(
    const ushort_t* __restrict__ A, const ushort_t* __restrict__ Bt,
    const float* __restrict__ bias, const float* __restrict__ resid,
    void* __restrict__ outp, int M, int N, int K) {
  constexpr int NFR = BN / 32;                 // n-frags per wave (4 or 2)
  __shared__ __align__(16) ushort_t As[2][128*32];
  __shared__ __align__(16) ushort_t Bs[2][BN*32];
  int bn = blockIdx.x, bm = blockIdx.y;
  int tid = threadIdx.x;
  int lane = tid & 63, wid = tid >> 6;
  int wr = (wid >> 1) * 64, wc = (wid & 1) * (BN / 2);
  int r = lane & 15, g = lane >> 4;
  int srow = tid >> 2, scc = (tid & 3) * 8;    // staging coords
  f32x4 acc[4][NFR] = {};
  int nk = K >> 5;

  const ushort_t* Abase = A  + (size_t)(bm*128) * K;
  const ushort_t* Bbase = Bt + (size_t)(bn*BN) * K;

#define STAGE_(bi, kt_)                                                        \
  do {                                                                         \
    gload_lds16(Abase + (size_t)srow * K + (kt_)*32 + scc, &As[bi][tid*8]);    \
    gload_lds16(Abase + (size_t)(srow + 64) * K + (kt_)*32 + scc,              \
                &As[bi][(tid + 256)*8]);                                       \
    gload_lds16(Bbase + (size_t)srow * K + (kt_)*32 + scc, &Bs[bi][tid*8]);    \
    if (BN == 128)                                                             \
      gload_lds16(Bbase + (size_t)(srow + 64) * K + (kt_)*32 + scc,            \
                  &Bs[bi][(tid + 256)*8]);                                     \
  } while (0)

  STAGE_(0, 0);
  __syncthreads();
  int buf = 0;
  for (int kt = 0; kt < nk; ++kt) {
    if (kt + 1 < nk) STAGE_(buf ^ 1, kt + 1);
    bf16x8 af[4], bfv[NFR];
#pragma unroll
    for (int m = 0; m < 4; ++m)
      af[m] = *(const bf16x8*)&As[buf][(wr + m*16 + r)*32 + g*8];
#pragma unroll
    for (int n = 0; n < NFR; ++n)
      bfv[n] = *(const bf16x8*)&Bs[buf][(wc + n*16 + r)*32 + g*8];
#pragma unroll
    for (int m = 0; m < 4; ++m)
#pragma unroll
      for (int n = 0; n < NFR; ++n)
        acc[m][n] = __builtin_amdgcn_mfma_f32_16x16x32_bf16(
            af[m], bfv[n], acc[m][n], 0, 0, 0);
    __syncthreads();   // drains stage(t+1) vmcnt + all LDS reads of buf
    buf ^= 1;
  }
#undef STAGE_

#pragma unroll
  for (int m = 0; m < 4; ++m)
#pragma unroll
    for (int n = 0; n < NFR; ++n)
#pragma unroll
      for (int e = 0; e < 4; ++e) {
        int row = bm*128 + wr + m*16 + g*4 + e;
        int col = bn*BN + wc + n*16 + r;
        float v = acc[m][n][e];
        if (BIAS)  v += bias[col];
        if (RESID) v += resid[(size_t)row * N + col];
        if (RELU)  v = fmaxf(v, 0.0f);
        if (OUTBF16) ((ushort_t*)outp)[(size_t)row * N + col] = f2bf(v);
        else         ((float*)outp)[(size_t)row * N + col]    = v;
      }
}

// -------------------------------------------------------- flash attention v3
// (unchanged — verified R7: swapped QK^T, in-register softmax, 16KB LDS)
__global__ __launch_bounds__(256) void attn_kernel(
    const ushort_t* __restrict__ q, const ushort_t* __restrict__ k,
    const ushort_t* __restrict__ vt, ushort_t* __restrict__ o, int ldq) {
  int bid = blockIdx.x;
  int qbb = 15 - (bid & 15);   // LPT: heavy q-blocks first
  int hh = (bid >> 4) & 15;
  int bb = bid >> 8;
  __shared__ __align__(16) ushort_t Ks[64*64];
  __shared__ __align__(16) ushort_t Vts[64*64];
  int tid = threadIdx.x, lane = tid & 63, w = tid >> 6;
  int qi = lane & 31, hi = lane >> 5;
  int qrow0 = qbb*128 + w*32;
  int qg = qrow0 + qi;                 // this lane's query row (in sequence)
  int lt = 2*qbb + (w >> 1);           // wave's last (diagonal) KV tile
  int nkv = 2*qbb + 2;

  const ushort_t* qbase = q + ((size_t)(bb*T_ + qg))*ldq + hh*64;
  bf16x8 qv[4];
#pragma unroll
  for (int c = 0; c < 4; ++c)
    qv[c] = *(const bf16x8*)(qbase + c*16 + hi*8);

  const ushort_t* kbase = k  + ((size_t)bb*T_)*ldq + hh*64;
  const ushort_t* vbase = vt + ((size_t)(bb*1024 + hh*64))*T_;

  int r0s = tid >> 3;                       // staging row 0..31
  int s0  = ((tid & 7) ^ (r0s & 7)) * 8;    // pre-swizzled source col (elems)

  f32x16 O0 = {}, O1 = {};
  float mrun = -1e30f, lrun = 0.f;

  for (int kt = 0; kt < nkv; ++kt) {
    gload_lds16(kbase + ((size_t)(kt*64 + r0s))*ldq + s0,      &Ks[tid*8]);
    gload_lds16(kbase + ((size_t)(kt*64 + r0s + 32))*ldq + s0, &Ks[(tid+256)*8]);
    gload_lds16(vbase + (size_t)r0s*T_ + kt*64 + s0,           &Vts[tid*8]);
    gload_lds16(vbase + (size_t)(r0s+32)*T_ + kt*64 + s0,      &Vts[(tid+256)*8]);
    __syncthreads();
    if (kt <= lt) {   // wave-uniform
      f32x16 a0 = {}, a1 = {};
#pragma unroll
      for (int c = 0; c < 4; ++c) {
        bf16x8 k0 = *(const bf16x8*)((char*)Ks + qswz(qi,      c*32 + hi*16));
        bf16x8 k1 = *(const bf16x8*)((char*)Ks + qswz(32 + qi, c*32 + hi*16));
        a0 = __builtin_amdgcn_mfma_f32_32x32x16_bf16(k0, qv[c], a0, 0, 0, 0);
        a1 = __builtin_amdgcn_mfma_f32_32x32x16_bf16(k1, qv[c], a1, 0, 0, 0);
      }
      if (kt == lt) {
        int kof = kt*64 + 4*hi;
#pragma unroll
        for (int rg = 0; rg < 16; ++rg) {
          int kp = kof + (rg & 3) + 8*(rg >> 2);
          if (kp > qg)      a0[rg] = -1e30f;
          if (kp + 32 > qg) a1[rg] = -1e30f;
        }
      }
      float tm = -1e30f;
#pragma unroll
      for (int rg = 0; rg < 16; ++rg) tm = fmaxf(tm, fmaxf(a0[rg], a1[rg]));
      tm = fmaxf(tm, __shfl_xor(tm, 32));
      float mnew = fmaxf(mrun, tm);
      float sf = exp2f((mrun - mnew) * C2_);
      mrun = mnew;
      float mc = mnew * C2_;
#pragma unroll
      for (int rg = 0; rg < 16; ++rg) {
        a0[rg] = exp2f(a0[rg]*C2_ - mc);
        a1[rg] = exp2f(a1[rg]*C2_ - mc);
      }
      float rs = 0.f;
#pragma unroll
      for (int rg = 0; rg < 16; ++rg) rs += a0[rg] + a1[rg];
      rs += __shfl_xor(rs, 32);
      lrun = lrun*sf + rs;
#pragma unroll
      for (int rg = 0; rg < 16; ++rg) { O0[rg] *= sf; O1[rg] *= sf; }
      bf16x8 pf[4];
#pragma unroll
      for (int kb = 0; kb < 2; ++kb)
#pragma unroll
        for (int jj = 0; jj < 2; ++jj) {
          int rb = jj*8;
          float v0 = kb ? a1[rb+0] : a0[rb+0], v1 = kb ? a1[rb+1] : a0[rb+1];
          float v2 = kb ? a1[rb+2] : a0[rb+2], v3 = kb ? a1[rb+3] : a0[rb+3];
          float v4 = kb ? a1[rb+4] : a0[rb+4], v5 = kb ? a1[rb+5] : a0[rb+5];
          float v6 = kb ? a1[rb+6] : a0[rb+6], v7 = kb ? a1[rb+7] : a0[rb+7];
          uint32_t d0 = pk2(v0, v1), d1 = pk2(v2, v3);
          uint32_t e0 = pk2(v4, v5), e1 = pk2(v6, v7);
          uint32_t pd0 = __shfl_xor(d0, 32), pd1 = __shfl_xor(d1, 32);
          uint32_t pe0 = __shfl_xor(e0, 32), pe1 = __shfl_xor(e1, 32);
          u32x4 fw;
          fw[0] = hi ? pe0 : d0;
          fw[1] = hi ? pe1 : d1;
          fw[2] = hi ? e0  : pd0;
          fw[3] = hi ? e1  : pd1;
          pf[kb*2 + jj] = __builtin_bit_cast(bf16x8, fw);
        }
#pragma unroll
      for (int kk = 0; kk < 4; ++kk) {
        bf16x8 vv0 = *(const bf16x8*)((char*)Vts + qswz(qi,      kk*32 + hi*16));
        bf16x8 vv1 = *(const bf16x8*)((char*)Vts + qswz(32 + qi, kk*32 + hi*16));
        O0 = __builtin_amdgcn_mfma_f32_32x32x16_bf16(vv0, pf[kk], O0, 0, 0, 0);
        O1 = __builtin_amdgcn_mfma_f32_32x32x16_bf16(vv1, pf[kk], O1, 0, 0, 0);
      }
    }
    __syncthreads();
  }
  float inv = 1.0f / lrun;
  ushort_t* ob = o + ((size_t)(bb*T_ + qg))*C_ + hh*64;
#pragma unroll
  for (int tq = 0; tq < 4; ++tq) {
    u32x2 st0, st1;
    st0[0] = pk2(O0[4*tq+0]*inv, O0[4*tq+1]*inv);
    st0[1] = pk2(O0[4*tq+2]*inv, O0[4*tq+3]*inv);
    st1[0] = pk2(O1[4*tq+0]*inv, O1[4*tq+1]*inv);
    st1[1] = pk2(O1[4*tq+2]*inv, O1[4*tq+3]*inv);
    *(u32x2*)(ob + 8*tq + 4*hi)      = st0;
    *(u32x2*)(ob + 32 + 8*tq + 4*hi) = st1;
  }
}

// ----------------------------------------------------------------- launch
extern "C" void kernel_launch(void* const* d_in, const int* in_sizes, int n_in,
                              void* d_out, int out_size, void* d_ws, size_t ws_size,
                              hipStream_t stream) {
  const float* x    = (const float*)d_in[0];
  const float* Wq   = (const float*)d_in[1];
  const float* Wk   = (const float*)d_in[2];
  const float* Wv   = (const float*)d_in[3];
  const float* Wo   = (const float*)d_in[4];
  const float* bo   = (const float*)d_in[5];
  const float* ln1g = (const float*)d_in[6];
  const float* ln1b = (const float*)d_in[7];
  const float* ln2g = (const float*)d_in[8];
  const float* ln2b = (const float*)d_in[9];
  const float* W1   = (const float*)d_in[10];
  const float* b1   = (const float*)d_in[11];
  const float* W2   = (const float*)d_in[12];
  const float* b2   = (const float*)d_in[13];

  char* ws = (char*)d_ws;
  ushort_t* h    = (ushort_t*)(ws + ((size_t)0  << 20));
  ushort_t* vt   = (ushort_t*)(ws + ((size_t)0  << 20));  // aliases h (dead)
  ushort_t* qkv  = (ushort_t*)(ws + ((size_t)8  << 20));
  ushort_t* ff   = (ushort_t*)(ws + ((size_t)0  << 20));
  ushort_t* attn = (ushort_t*)(ws + ((size_t)32 << 20));
  float*    x2   = (float*)   (ws + ((size_t)40 << 20));
  ushort_t* h2   = (ushort_t*)(ws + ((size_t)56 << 20));
  ushort_t* wqt  = (ushort_t*)(ws + ((size_t)64 << 20));  // [3072][1024] fused
  ushort_t* wkt  = (ushort_t*)(ws + ((size_t)66 << 20));
  ushort_t* wvt  = (ushort_t*)(ws + ((size_t)68 << 20));
  ushort_t* wot  = (ushort_t*)(ws + ((size_t)70 << 20));
  ushort_t* w1t  = (ushort_t*)(ws + ((size_t)72 << 20));
  ushort_t* w2t  = (ushort_t*)(ws + ((size_t)80 << 20));
  float* out = (float*)d_out;

  tcast_kernel<<<dim3(32, 32),  256, 0, stream>>>(Wq, wqt, 1024, 1024);
  tcast_kernel<<<dim3(32, 32),  256, 0, stream>>>(Wk, wkt, 1024, 1024);
  tcast_kernel<<<dim3(32, 32),  256, 0, stream>>>(Wv, wvt, 1024, 1024);
  tcast_kernel<<<dim3(32, 32),  256, 0, stream>>>(Wo, wot, 1024, 1024);
  tcast_kernel<<<dim3(128, 32), 256, 0, stream>>>(W1, w1t, 1024, 4096);
  tcast_kernel<<<dim3(32, 128), 256, 0, stream>>>(W2, w2t, 4096, 1024);

  lnorm_kernel<<<M_, 256, 0, stream>>>(x, ln1g, ln1b, h);

  // fused QKV: qkv[M][3072] = h @ [Wq|Wk|Wv]
  gemm_kernel<128,0,0,0,1><<<dim3(24, 32), 256, 0, stream>>>(h, wqt, nullptr, nullptr, qkv, M_, 3*C_, C_);

  // V^T pre-pass (h dead; vt aliases it)
  vtrans_kernel<<<dim3(64, 32, 2), 256, 0, stream>>>(qkv, vt);

  attn_kernel<<<512, 256, 0, stream>>>(qkv, qkv + C_, vt, attn, 3*C_);

  // x2 = x + attn @ Wo + bo   (f32)  — BN=64: 512 blocks, 2/CU
  gemm_kernel<64,1,0,1,0><<<dim3(16, 32), 256, 0, stream>>>(attn, wot, bo, x, x2, M_, C_, C_);

  lnorm_kernel<<<M_, 256, 0, stream>>>(x2, ln2g, ln2b, h2);

  // ff = relu(h2 @ W1 + b1)  (bf16)
  gemm_kernel<128,1,1,0,1><<<dim3(32, 32), 256, 0, stream>>>(h2, w1t, b1, nullptr, ff, M_, FF_, C_);

  // out = x2 + ff @ W2 + b2  (f32)  — BN=64: 512 blocks, 2/CU
  gemm_kernel<64,1,0,1,0><<<dim3(16, 32), 256, 0, stream>>>(ff, w2t, b2, x2, out, M_, C_, FF_);
}

// Round 10
// 401.693 us; speedup vs baseline: 1.2949x; 1.0501x over previous
//
#include <hip/hip_runtime.h>
#include <hip/hip_bf16.h>
#include <stdint.h>

#define B_  2
#define T_  2048
#define C_  1024
#define H_  16
#define HD_ 64
#define M_  4096   // B*T
#define FF_ 4096

typedef unsigned short ushort_t;
typedef __bf16 bf16x8 __attribute__((ext_vector_type(8)));
typedef float  f32x4  __attribute__((ext_vector_type(4)));
typedef float  f32x16 __attribute__((ext_vector_type(16)));
typedef unsigned int u32x2 __attribute__((ext_vector_type(2)));
typedef unsigned int u32x4 __attribute__((ext_vector_type(4)));

#define C2_ 0.1803368801111204f   // (1/sqrt(64)) * log2(e)

__device__ inline ushort_t f2bf(float f) {
  uint32_t u = __builtin_bit_cast(uint32_t, f);
  u += 0x7fffu + ((u >> 16) & 1u);
  return (ushort_t)(u >> 16);
}
__device__ inline uint32_t pk2(float lo, float hi) {
  return (uint32_t)f2bf(lo) | ((uint32_t)f2bf(hi) << 16);
}

// async global->LDS, 16B per lane (dwordx4 variant)
__device__ inline void gload_lds16(const void* g, void* l) {
  __builtin_amdgcn_global_load_lds(
      (const __attribute__((address_space(1))) uint32_t*)g,
      (__attribute__((address_space(3))) uint32_t*)l, 16, 0, 0);
}

// 128B-row LDS tiles (64 bf16 cols): logical col-slot c lives at phys slot
// c ^ (row&7). Writes are DMA-linear with pre-swizzled SOURCE; reads use this.
__device__ inline int qswz(int row, int byte_in_row) {
  return row * 128 + (byte_in_row ^ ((row & 7) << 4));
}

// ---------------------------------------------------------------- LayerNorm
__global__ __launch_bounds__(256) void lnorm_kernel(
    const float* __restrict__ x, const float* __restrict__ g,
    const float* __restrict__ b, ushort_t* __restrict__ o) {
  int row = blockIdx.x;
  int tid = threadIdx.x;
  const float4* xr = (const float4*)(x + (size_t)row * C_);
  float4 xv = xr[tid];
  float s  = xv.x + xv.y + xv.z + xv.w;
  float s2 = xv.x*xv.x + xv.y*xv.y + xv.z*xv.z + xv.w*xv.w;
#pragma unroll
  for (int off = 32; off; off >>= 1) {
    s  += __shfl_down(s,  off);
    s2 += __shfl_down(s2, off);
  }
  __shared__ float rs[4], rq[4];
  int wid = tid >> 6;
  if ((tid & 63) == 0) { rs[wid] = s; rq[wid] = s2; }
  __syncthreads();
  float tot  = rs[0] + rs[1] + rs[2] + rs[3];
  float tot2 = rq[0] + rq[1] + rq[2] + rq[3];
  float mu   = tot * (1.0f / C_);
  float var  = tot2 * (1.0f / C_) - mu * mu;
  float rstd = rsqrtf(var + 1e-5f);
  float4 gv = ((const float4*)g)[tid];
  float4 bv = ((const float4*)b)[tid];
  float y0 = (xv.x - mu) * rstd * gv.x + bv.x;
  float y1 = (xv.y - mu) * rstd * gv.y + bv.y;
  float y2 = (xv.z - mu) * rstd * gv.z + bv.z;
  float y3 = (xv.w - mu) * rstd * gv.w + bv.w;
  uint2 pk;
  pk.x = (uint32_t)f2bf(y0) | ((uint32_t)f2bf(y1) << 16);
  pk.y = (uint32_t)f2bf(y2) | ((uint32_t)f2bf(y3) << 16);
  *(uint2*)(o + (size_t)row * C_ + tid * 4) = pk;
}

// ------------------------------------------- transpose + f32->bf16 cast of W
__global__ __launch_bounds__(256) void tcast_kernel(
    const float* __restrict__ W, ushort_t* __restrict__ Wt, int K, int N) {
  __shared__ float t[32][33];
  int bn = blockIdx.x, bk = blockIdx.y;
  int tx = threadIdx.x & 31, ty = threadIdx.x >> 5;
#pragma unroll
  for (int i = 0; i < 4; ++i)
    t[ty + i*8][tx] = W[(size_t)(bk*32 + ty + i*8) * N + bn*32 + tx];
  __syncthreads();
#pragma unroll
  for (int i = 0; i < 4; ++i)
    Wt[(size_t)(bn*32 + ty + i*8) * K + bk*32 + tx] = f2bf(t[tx][ty + i*8]);
}

// -------------------------------------- V transpose: qkv V-part -> vt[c][tok]
__global__ __launch_bounds__(256) void vtrans_kernel(
    const ushort_t* __restrict__ qkv, ushort_t* __restrict__ vt) {
  __shared__ ushort_t t[32][33];
  int tt = blockIdx.x;   // tok tile (32)
  int cc = blockIdx.y;   // c tile (32)
  int bb = blockIdx.z;
  int tx = threadIdx.x & 31, ty = threadIdx.x >> 5;
#pragma unroll
  for (int i = 0; i < 4; ++i)
    t[ty + i*8][tx] = qkv[(size_t)(bb*T_ + tt*32 + ty + i*8)*3072 + 2048 + cc*32 + tx];
  __syncthreads();
  int crow = threadIdx.x >> 4;
  int ucol = threadIdx.x & 15;
#pragma unroll
  for (int i = 0; i < 2; ++i) {
    int c = crow + i*16;
    uint32_t vlo = t[ucol*2][c], vhi = t[ucol*2 + 1][c];
    *(uint32_t*)&vt[(size_t)(bb*1024 + cc*32 + c)*T_ + tt*32 + ucol*2] =
        vlo | (vhi << 16);
  }
}

// ------------------------------------------------------------------- GEMM
// (unchanged — verified R9: 2-phase dbuf, one barrier/iter)
template<int BN, int BIAS, int RELU, int RESID, int OUTBF16>
__global__ __launch_bounds__(256) void gemm_kernel(
    const ushort_t* __restrict__ A, const ushort_t* __restrict__ Bt,
    const float* __restrict__ bias, const float* __restrict__ resid,
    void* __restrict__ outp, int M, int N, int K) {
  constexpr int NFR = BN / 32;                 // n-frags per wave (4 or 2)
  __shared__ __align__(16) ushort_t As[2][128*32];
  __shared__ __align__(16) ushort_t Bs[2][BN*32];
  int bn = blockIdx.x, bm = blockIdx.y;
  int tid = threadIdx.x;
  int lane = tid & 63, wid = tid >> 6;
  int wr = (wid >> 1) * 64, wc = (wid & 1) * (BN / 2);
  int r = lane & 15, g = lane >> 4;
  int srow = tid >> 2, scc = (tid & 3) * 8;    // staging coords
  f32x4 acc[4][NFR] = {};
  int nk = K >> 5;

  const ushort_t* Abase = A  + (size_t)(bm*128) * K;
  const ushort_t* Bbase = Bt + (size_t)(bn*BN) * K;

#define STAGE_(bi, kt_)                                                        \
  do {                                                                         \
    gload_lds16(Abase + (size_t)srow * K + (kt_)*32 + scc, &As[bi][tid*8]);    \
    gload_lds16(Abase + (size_t)(srow + 64) * K + (kt_)*32 + scc,              \
                &As[bi][(tid + 256)*8]);                                       \
    gload_lds16(Bbase + (size_t)srow * K + (kt_)*32 + scc, &Bs[bi][tid*8]);    \
    if (BN == 128)                                                             \
      gload_lds16(Bbase + (size_t)(srow + 64) * K + (kt_)*32 + scc,            \
                  &Bs[bi][(tid + 256)*8]);                                     \
  } while (0)

  STAGE_(0, 0);
  __syncthreads();
  int buf = 0;
  for (int kt = 0; kt < nk; ++kt) {
    if (kt + 1 < nk) STAGE_(buf ^ 1, kt + 1);
    bf16x8 af[4], bfv[NFR];
#pragma unroll
    for (int m = 0; m < 4; ++m)
      af[m] = *(const bf16x8*)&As[buf][(wr + m*16 + r)*32 + g*8];
#pragma unroll
    for (int n = 0; n < NFR; ++n)
      bfv[n] = *(const bf16x8*)&Bs[buf][(wc + n*16 + r)*32 + g*8];
#pragma unroll
    for (int m = 0; m < 4; ++m)
#pragma unroll
      for (int n = 0; n < NFR; ++n)
        acc[m][n] = __builtin_amdgcn_mfma_f32_16x16x32_bf16(
            af[m], bfv[n], acc[m][n], 0, 0, 0);
    __syncthreads();   // drains stage(t+1) vmcnt + all LDS reads of buf
    buf ^= 1;
  }
#undef STAGE_

#pragma unroll
  for (int m = 0; m < 4; ++m)
#pragma unroll
    for (int n = 0; n < NFR; ++n)
#pragma unroll
      for (int e = 0; e < 4; ++e) {
        int row = bm*128 + wr + m*16 + g*4 + e;
        int col = bn*BN + wc + n*16 + r;
        float v = acc[m][n][e];
        if (BIAS)  v += bias[col];
        if (RESID) v += resid[(size_t)row * N + col];
        if (RELU)  v = fmaxf(v, 0.0f);
        if (OUTBF16) ((ushort_t*)outp)[(size_t)row * N + col] = f2bf(v);
        else         ((float*)outp)[(size_t)row * N + col]    = v;
      }
}

// -------------------------------------------------------- flash attention v4
// v3 (swapped QK^T, in-register softmax) + double-buffered K/V staging
// (1 barrier/tile) + balanced XCD-aware block mapping:
//   xcd=bid&7, hh=xcd+8*hh_hi  -> same-(b,h) blocks share an XCD's L2;
//   qbb = bb ? 15-q4 : q4      -> co-resident blocks (bid vs bid+256 or +8k)
//                                 get complementary causal work (34 units/CU).
__global__ __launch_bounds__(256) void attn_kernel(
    const ushort_t* __restrict__ q, const ushort_t* __restrict__ k,
    const ushort_t* __restrict__ vt, ushort_t* __restrict__ o, int ldq) {
  int bid = blockIdx.x;
  int xcd = bid & 7, kk_ = bid >> 3;
  int q4 = kk_ & 15, rest = kk_ >> 4;   // rest in [0,4)
  int hh = xcd + 8*(rest & 1);
  int bb = rest >> 1;
  int qbb = bb ? (15 - q4) : q4;
  __shared__ __align__(16) ushort_t Ks[2][64*64];
  __shared__ __align__(16) ushort_t Vts[2][64*64];
  int tid = threadIdx.x, lane = tid & 63, w = tid >> 6;
  int qi = lane & 31, hi = lane >> 5;
  int qrow0 = qbb*128 + w*32;
  int qg = qrow0 + qi;                 // this lane's query row (in sequence)
  int lt = 2*qbb + (w >> 1);           // wave's last (diagonal) KV tile
  int nkv = 2*qbb + 2;

  const ushort_t* qbase = q + ((size_t)(bb*T_ + qg))*ldq + hh*64;
  bf16x8 qv[4];
#pragma unroll
  for (int c = 0; c < 4; ++c)
    qv[c] = *(const bf16x8*)(qbase + c*16 + hi*8);

  const ushort_t* kbase = k  + ((size_t)bb*T_)*ldq + hh*64;
  const ushort_t* vbase = vt + ((size_t)(bb*1024 + hh*64))*T_;

  int r0s = tid >> 3;                       // staging row 0..31
  int s0  = ((tid & 7) ^ (r0s & 7)) * 8;    // pre-swizzled source col (elems)

  f32x16 O0 = {}, O1 = {};
  float mrun = -1e30f, lrun = 0.f;

#define AST_(bi, kt_)                                                          \
  do {                                                                         \
    gload_lds16(kbase + ((size_t)((kt_)*64 + r0s))*ldq + s0, &Ks[bi][tid*8]);  \
    gload_lds16(kbase + ((size_t)((kt_)*64 + r0s + 32))*ldq + s0,              \
                &Ks[bi][(tid+256)*8]);                                         \
    gload_lds16(vbase + (size_t)r0s*T_ + (kt_)*64 + s0, &Vts[bi][tid*8]);      \
    gload_lds16(vbase + (size_t)(r0s+32)*T_ + (kt_)*64 + s0,                   \
                &Vts[bi][(tid+256)*8]);                                        \
  } while (0)

  AST_(0, 0);
  __syncthreads();
  int buf = 0;
  for (int kt = 0; kt < nkv; ++kt) {
    if (kt + 1 < nkv) AST_(buf ^ 1, kt + 1);
    if (kt <= lt) {   // wave-uniform
      f32x16 a0 = {}, a1 = {};
#pragma unroll
      for (int c = 0; c < 4; ++c) {
        bf16x8 k0 = *(const bf16x8*)((char*)&Ks[buf][0] + qswz(qi,      c*32 + hi*16));
        bf16x8 k1 = *(const bf16x8*)((char*)&Ks[buf][0] + qswz(32 + qi, c*32 + hi*16));
        a0 = __builtin_amdgcn_mfma_f32_32x32x16_bf16(k0, qv[c], a0, 0, 0, 0);
        a1 = __builtin_amdgcn_mfma_f32_32x32x16_bf16(k1, qv[c], a1, 0, 0, 0);
      }
      if (kt == lt) {
        int kof = kt*64 + 4*hi;
#pragma unroll
        for (int rg = 0; rg < 16; ++rg) {
          int kp = kof + (rg & 3) + 8*(rg >> 2);
          if (kp > qg)      a0[rg] = -1e30f;
          if (kp + 32 > qg) a1[rg] = -1e30f;
        }
      }
      float tm = -1e30f;
#pragma unroll
      for (int rg = 0; rg < 16; ++rg) tm = fmaxf(tm, fmaxf(a0[rg], a1[rg]));
      tm = fmaxf(tm, __shfl_xor(tm, 32));
      float mnew = fmaxf(mrun, tm);
      float sf = exp2f((mrun - mnew) * C2_);
      mrun = mnew;
      float mc = mnew * C2_;
#pragma unroll
      for (int rg = 0; rg < 16; ++rg) {
        a0[rg] = exp2f(a0[rg]*C2_ - mc);
        a1[rg] = exp2f(a1[rg]*C2_ - mc);
      }
      float rs = 0.f;
#pragma unroll
      for (int rg = 0; rg < 16; ++rg) rs += a0[rg] + a1[rg];
      rs += __shfl_xor(rs, 32);
      lrun = lrun*sf + rs;
#pragma unroll
      for (int rg = 0; rg < 16; ++rg) { O0[rg] *= sf; O1[rg] *= sf; }
      bf16x8 pf[4];
#pragma unroll
      for (int kb = 0; kb < 2; ++kb)
#pragma unroll
        for (int jj = 0; jj < 2; ++jj) {
          int rb = jj*8;
          float v0 = kb ? a1[rb+0] : a0[rb+0], v1 = kb ? a1[rb+1] : a0[rb+1];
          float v2 = kb ? a1[rb+2] : a0[rb+2], v3 = kb ? a1[rb+3] : a0[rb+3];
          float v4 = kb ? a1[rb+4] : a0[rb+4], v5 = kb ? a1[rb+5] : a0[rb+5];
          float v6 = kb ? a1[rb+6] : a0[rb+6], v7 = kb ? a1[rb+7] : a0[rb+7];
          uint32_t d0 = pk2(v0, v1), d1 = pk2(v2, v3);
          uint32_t e0 = pk2(v4, v5), e1 = pk2(v6, v7);
          uint32_t pd0 = __shfl_xor(d0, 32), pd1 = __shfl_xor(d1, 32);
          uint32_t pe0 = __shfl_xor(e0, 32), pe1 = __shfl_xor(e1, 32);
          u32x4 fw;
          fw[0] = hi ? pe0 : d0;
          fw[1] = hi ? pe1 : d1;
          fw[2] = hi ? e0  : pd0;
          fw[3] = hi ? e1  : pd1;
          pf[kb*2 + jj] = __builtin_bit_cast(bf16x8, fw);
        }
#pragma unroll
      for (int kk = 0; kk < 4; ++kk) {
        bf16x8 vv0 = *(const bf16x8*)((char*)&Vts[buf][0] + qswz(qi,      kk*32 + hi*16));
        bf16x8 vv1 = *(const bf16x8*)((char*)&Vts[buf][0] + qswz(32 + qi, kk*32 + hi*16));
        O0 = __builtin_amdgcn_mfma_f32_32x32x16_bf16(vv0, pf[kk], O0, 0, 0, 0);
        O1 = __builtin_amdgcn_mfma_f32_32x32x16_bf16(vv1, pf[kk], O1, 0, 0, 0);
      }
    }
    __syncthreads();   // drains stage(kt+1) vmcnt + all LDS reads of buf
    buf ^= 1;
  }
#undef AST_
  float inv = 1.0f / lrun;
  ushort_t* ob = o + ((size_t)(bb*T_ + qg))*C_ + hh*64;
#pragma unroll
  for (int tq = 0; tq < 4; ++tq) {
    u32x2 st0, st1;
    st0[0] = pk2(O0[4*tq+0]*inv, O0[4*tq+1]*inv);
    st0[1] = pk2(O0[4*tq+2]*inv, O0[4*tq+3]*inv);
    st1[0] = pk2(O1[4*tq+0]*inv, O1[4*tq+1]*inv);
    st1[1] = pk2(O1[4*tq+2]*inv, O1[4*tq+3]*inv);
    *(u32x2*)(ob + 8*tq + 4*hi)      = st0;
    *(u32x2*)(ob + 32 + 8*tq + 4*hi) = st1;
  }
}

// ----------------------------------------------------------------- launch
extern "C" void kernel_launch(void* const* d_in, const int* in_sizes, int n_in,
                              void* d_out, int out_size, void* d_ws, size_t ws_size,
                              hipStream_t stream) {
  const float* x    = (const float*)d_in[0];
  const float* Wq   = (const float*)d_in[1];
  const float* Wk   = (const float*)d_in[2];
  const float* Wv   = (const float*)d_in[3];
  const float* Wo   = (const float*)d_in[4];
  const float* bo   = (const float*)d_in[5];
  const float* ln1g = (const float*)d_in[6];
  const float* ln1b = (const float*)d_in[7];
  const float* ln2g = (const float*)d_in[8];
  const float* ln2b = (const float*)d_in[9];
  const float* W1   = (const float*)d_in[10];
  const float* b1   = (const float*)d_in[11];
  const float* W2   = (const float*)d_in[12];
  const float* b2   = (const float*)d_in[13];

  char* ws = (char*)d_ws;
  ushort_t* h    = (ushort_t*)(ws + ((size_t)0  << 20));
  ushort_t* vt   = (ushort_t*)(ws + ((size_t)0  << 20));  // aliases h (dead)
  ushort_t* qkv  = (ushort_t*)(ws + ((size_t)8  << 20));
  ushort_t* ff   = (ushort_t*)(ws + ((size_t)0  << 20));
  ushort_t* attn = (ushort_t*)(ws + ((size_t)32 << 20));
  float*    x2   = (float*)   (ws + ((size_t)40 << 20));
  ushort_t* h2   = (ushort_t*)(ws + ((size_t)56 << 20));
  ushort_t* wqt  = (ushort_t*)(ws + ((size_t)64 << 20));  // [3072][1024] fused
  ushort_t* wkt  = (ushort_t*)(ws + ((size_t)66 << 20));
  ushort_t* wvt  = (ushort_t*)(ws + ((size_t)68 << 20));
  ushort_t* wot  = (ushort_t*)(ws + ((size_t)70 << 20));
  ushort_t* w1t  = (ushort_t*)(ws + ((size_t)72 << 20));
  ushort_t* w2t  = (ushort_t*)(ws + ((size_t)80 << 20));
  float* out = (float*)d_out;

  tcast_kernel<<<dim3(32, 32),  256, 0, stream>>>(Wq, wqt, 1024, 1024);
  tcast_kernel<<<dim3(32, 32),  256, 0, stream>>>(Wk, wkt, 1024, 1024);
  tcast_kernel<<<dim3(32, 32),  256, 0, stream>>>(Wv, wvt, 1024, 1024);
  tcast_kernel<<<dim3(32, 32),  256, 0, stream>>>(Wo, wot, 1024, 1024);
  tcast_kernel<<<dim3(128, 32), 256, 0, stream>>>(W1, w1t, 1024, 4096);
  tcast_kernel<<<dim3(32, 128), 256, 0, stream>>>(W2, w2t, 4096, 1024);

  lnorm_kernel<<<M_, 256, 0, stream>>>(x, ln1g, ln1b, h);

  // fused QKV: qkv[M][3072] = h @ [Wq|Wk|Wv]
  gemm_kernel<128,0,0,0,1><<<dim3(24, 32), 256, 0, stream>>>(h, wqt, nullptr, nullptr, qkv, M_, 3*C_, C_);

  // V^T pre-pass (h dead; vt aliases it)
  vtrans_kernel<<<dim3(64, 32, 2), 256, 0, stream>>>(qkv, vt);

  attn_kernel<<<512, 256, 0, stream>>>(qkv, qkv + C_, vt, attn, 3*C_);

  // x2 = x + attn @ Wo + bo   (f32)  — BN=64: 512 blocks, 2/CU
  gemm_kernel<64,1,0,1,0><<<dim3(16, 32), 256, 0, stream>>>(attn, wot, bo, x, x2, M_, C_, C_);

  lnorm_kernel<<<M_, 256, 0, stream>>>(x2, ln2g, ln2b, h2);

  // ff = relu(h2 @ W1 + b1)  (bf16)
  gemm_kernel<128,1,1,0,1><<<dim3(32, 32), 256, 0, stream>>>(h2, w1t, b1, nullptr, ff, M_, FF_, C_);

  // out = x2 + ff @ W2 + b2  (f32)  — BN=64: 512 blocks, 2/CU
  gemm_kernel<64,1,0,1,0><<<dim3(16, 32), 256, 0, stream>>>(ff, w2t, b2, x2, out, M_, C_, FF_);
}